// Round 7
// baseline (233.330 us; speedup 1.0000x reference)
//
#include <hip/hip_runtime.h>
#include <math.h>

#define BATCH 4
#define SEQ 2048
#define DMODEL 256
#define NH 4
#define HD 64
#define MROWS 8192
#define QKSCALE 0.4246608905f  // sqrt(0.125 * log2(e)): qk pre-scaled => exp2 direct

typedef short bf16x8 __attribute__((ext_vector_type(8)));
typedef float f32x4 __attribute__((ext_vector_type(4)));
typedef unsigned short us;

#if __has_builtin(__builtin_amdgcn_exp2f)
#define EXP2(x) __builtin_amdgcn_exp2f(x)
#else
#define EXP2(x) exp2f(x)
#endif

__device__ __forceinline__ us f2bf(float x) {  // RNE
  union { float f; unsigned int u; } v;
  v.f = x;
  unsigned int r = (v.u + 0x7FFF + ((v.u >> 16) & 1)) >> 16;
  return (us)r;
}
__device__ __forceinline__ float bf2f(us u) {
  union { unsigned int u; float f; } v;
  v.u = ((unsigned int)u) << 16;
  return v.f;
}
__device__ __forceinline__ unsigned int fbits(float x) {
  union { float f; unsigned int u; } v;
  v.f = x;
  return v.u;
}
// v_perm pack: [bf16_trunc(lo) | bf16_trunc(hi)<<16] in one instruction.
__device__ __forceinline__ unsigned int pk2bf(float lo, float hi) {
  return __builtin_amdgcn_perm(fbits(hi), fbits(lo), 0x07060302u);
}
// Async global->LDS DMA, 16B/lane; lane i lands at base + i*16.
__device__ __forceinline__ void dma16(const void* g, void* l) {
  auto gp = (const __attribute__((address_space(1))) unsigned int*)(unsigned long long)(uintptr_t)g;
  auto lp = (__attribute__((address_space(3))) unsigned int*)(unsigned int)(uintptr_t)l;
  __builtin_amdgcn_global_load_lds(gp, lp, 16, 0, 0);
}

// ---------------------------------------------------------------------------
// prep_k: one dispatch for all host-side prep.
//   blocks [0,4096):    cast x0,x1 fp32->bf16
//   blocks [4096,5634): transpose-cast weights -> Wqvt/W1t(top)/W3t + bias_qv
//   blocks [5634,5891): wcomb: W1t[j][256+i] = (Wout@W0_bot)^T, bias1
// ---------------------------------------------------------------------------
__global__ __launch_bounds__(256) void prep_k(
    const float* __restrict__ x0, const float* __restrict__ x1,
    const float* __restrict__ Wqk, const float* __restrict__ Wv,
    const float* __restrict__ W0, const float* __restrict__ W3,
    const float* __restrict__ Wout,
    const float* __restrict__ bqk, const float* __restrict__ bv,
    const float* __restrict__ b0, const float* __restrict__ bout,
    us* __restrict__ x0b, us* __restrict__ x1b,
    us* __restrict__ Wqvt, us* __restrict__ W1t, us* __restrict__ W3t,
    float* __restrict__ bias_qv, float* __restrict__ bias1) {
  const int bid = blockIdx.x, t = threadIdx.x;
  if (bid < 4096) {
    const int n4 = (MROWS * DMODEL) / 4;
    int i = bid * 256 + t;
    const float* src = (i < n4) ? x0 : x1;
    us* dst = (i < n4) ? x0b : x1b;
    int j = (i < n4) ? i : i - n4;
    float4 v = *(const float4*)&src[j * 4];
    ushort4 o = {f2bf(v.x), f2bf(v.y), f2bf(v.z), f2bf(v.w)};
    *(ushort4*)&dst[j * 4] = o;
  } else if (bid < 5634) {
    int gid = (bid - 4096) * 256 + t;
    if (gid < 65536) {
      int k = gid >> 8, j = gid & 255;
      Wqvt[j * 256 + k] = f2bf(Wqk[gid]);
    } else if (gid < 131072) {
      int i = gid - 65536;
      int k = i >> 8, j = i & 255;
      Wqvt[(256 + j) * 256 + k] = f2bf(Wv[i]);
    } else if (gid < 262144) {
      int i = gid - 131072;
      int k = i >> 9, j = i & 511;
      W1t[j * 512 + k] = f2bf(W0[i]);
    } else if (gid < 393216) {
      int i = gid - 262144;
      int k = i >> 8, j = i & 255;
      W3t[j * 512 + k] = f2bf(W3[i]);
    } else if (gid < 393728) {
      int j = gid - 393216;
      bias_qv[j] = (j < 256) ? bqk[j] : bv[j - 256];
    }
  } else {
    int i = bid - 5634;  // [0,257)
    if (i < 256) {
      float a0 = 0.f, a1 = 0.f;
      for (int k0 = 0; k0 < 256; k0 += 8) {
        float wk[8], r0[8], r1[8];
#pragma unroll
        for (int u = 0; u < 8; ++u) {
          wk[u] = Wout[i * 256 + k0 + u];
          const float* row = &W0[(size_t)(256 + k0 + u) * 512];
          r0[u] = row[t];
          r1[u] = row[t + 256];
        }
#pragma unroll
        for (int u = 0; u < 8; ++u) { a0 += wk[u] * r0[u]; a1 += wk[u] * r1[u]; }
      }
      W1t[t * 512 + 256 + i] = f2bf(a0);
      W1t[(t + 256) * 512 + 256 + i] = f2bf(a1);
    } else {
      float a0 = b0[t], a1 = b0[t + 256];
      for (int k = 0; k < 256; ++k) {
        float bk = bout[k];
        const float* row = &W0[(size_t)(256 + k) * 512];
        a0 += bk * row[t];
        a1 += bk * row[t + 256];
      }
      bias1[t] = a0;
      bias1[t + 256] = a1;
    }
  }
}

// ---------------------------------------------------------------------------
// gemm5: MFMA bf16 GEMM with DOUBLE-BUFFERED DMA prefetch and XCD-aware
// block remap (same-A-tile blocks colocate on one XCD for L2 reuse).
// 128-row tile; 4 waves. MODE 0/1: 128-col tile, wave = 64x64 quadrant.
// MODE 2: 64-col tile, wave = 32x64 band.
//   MODE 0 (QV, N=512): coltile<2 -> qk bf16 *QKSCALE; >=2 -> Vt transposed
//   MODE 1 (FFN1, N=512): A = concat(Ax, Am) along K (lda=256 each)
//   MODE 2 (FFN2, N=256): fp32 out = resid + A@W + bias
// All grids: (64, 4, 2) = 512 blocks.
// ---------------------------------------------------------------------------
template <int MODE>
__global__ __launch_bounds__(256) void gemm5(
    const us* __restrict__ A0, const us* __restrict__ A1,
    const us* __restrict__ Am0, const us* __restrict__ Am1,
    const us* __restrict__ Wt, const float* __restrict__ bias,
    const float* __restrict__ r0_, const float* __restrict__ r1_,
    void* __restrict__ C0_, void* __restrict__ C1_,
    void* __restrict__ V0_, void* __restrict__ V1_, int K) {
  constexpr int CT = (MODE == 2) ? 64 : 128;   // col-tile
  constexpr int BG = (CT / 16) * 2;            // B granules: 16 or 8
  constexpr int BUFS = 8192 + BG * 512;        // shorts per buffer
  __shared__ us lds[2 * BUFS];

  const int t = threadIdx.x, w = t >> 6, lane = t & 63;
  const int qd = lane >> 4, l15 = lane & 15;

  // XCD-aware remap: flat%8 ~ XCD; colocate all 4 col-tiles of one (x,z).
  const int flat = blockIdx.x + 64 * (blockIdx.y + 4 * blockIdx.z);
  const int xcd = flat & 7, slot = flat >> 3;     // slot in [0,64)
  const int xz = (xcd << 4) + (slot >> 2);        // [0,128)
  const int bx = xz & 63, z = xz >> 6, coltile = slot & 3;
  const int row0 = bx * 128, col0 = coltile * CT;

  const us* Ax = z ? A1 : A0;
  const us* Am = z ? Am1 : Am0;
  const int qr = (MODE == 2) ? w : (w >> 1);
  const int qc = (MODE == 2) ? 0 : (w & 1);
  constexpr int MI = (MODE == 2) ? 2 : 4;

  f32x4 acc[MI][4];
#pragma unroll
  for (int i = 0; i < MI; ++i)
#pragma unroll
    for (int j = 0; j < 4; ++j) acc[i][j] = (f32x4){0.f, 0.f, 0.f, 0.f};

  const int NK = K >> 6;
  // Prologue: stage k-tile 0 into buffer 0.
#pragma unroll
  for (int pp = 0; pp < (16 + BG) / 4; ++pp) {
    int g = pp * 4 + w;
    const us* src;
    if (g < 16) {
      int tm = g >> 1, s = g & 1;
      int kk = s * 32 + qd * 8;
      src = &((MODE == 1) ? Ax : Ax)[(size_t)(row0 + tm * 16 + l15) * ((MODE == 1) ? 256 : K) + kk];
    } else {
      int gb = g - 16, tn = gb >> 1, s = gb & 1;
      src = &Wt[(size_t)(col0 + tn * 16 + l15) * K + s * 32 + qd * 8];
    }
    dma16(src, &lds[g * 512]);
  }
  __syncthreads();

  int bsel = 0;
  for (int it = 0; it < NK; ++it) {
    if (it + 1 < NK) {
      int k0 = (it + 1) << 6;
#pragma unroll
      for (int pp = 0; pp < (16 + BG) / 4; ++pp) {
        int g = pp * 4 + w;
        const us* src;
        if (g < 16) {
          int tm = g >> 1, s = g & 1;
          const us* Ap = Ax;
          int kk = k0 + s * 32 + qd * 8, lda = K;
          if (MODE == 1) {
            Ap = (k0 < 256) ? Ax : Am;
            kk &= 255;
            lda = 256;
          }
          src = &Ap[(size_t)(row0 + tm * 16 + l15) * lda + kk];
        } else {
          int gb = g - 16, tn = gb >> 1, s = gb & 1;
          src = &Wt[(size_t)(col0 + tn * 16 + l15) * K + k0 + s * 32 + qd * 8];
        }
        dma16(src, &lds[(bsel ^ 1) * BUFS + g * 512]);
      }
    }
    const us* L = &lds[bsel * BUFS];
#pragma unroll
    for (int s = 0; s < 2; ++s) {
      bf16x8 af[MI], bfr[4];
#pragma unroll
      for (int i = 0; i < MI; ++i)
        af[i] = *(const bf16x8*)&L[(((qr * MI + i) * 2 + s) * 64 + lane) * 8];
#pragma unroll
      for (int j = 0; j < 4; ++j)
        bfr[j] = *(const bf16x8*)&L[8192 + (((qc * 4 + j) * 2 + s) * 64 + lane) * 8];
#pragma unroll
      for (int i = 0; i < MI; ++i)
#pragma unroll
        for (int j = 0; j < 4; ++j)
          acc[i][j] = __builtin_amdgcn_mfma_f32_16x16x32_bf16(af[i], bfr[j], acc[i][j], 0, 0, 0);
    }
    __syncthreads();
    bsel ^= 1;
  }

  // Epilogue. C-layout: row = row0 + qr*(MI*16) + i*16 + qd*4 + r,
  //                     col = col0 + qc*64 + j*16 + l15.
  if (MODE == 0 && coltile >= 2) {
    // Vt transposed write via LDS bounce (stride 130: conflict-free).
    int base = qc * 8320;
#pragma unroll
    for (int j = 0; j < 4; ++j) {
      int col = col0 + qc * 64 + j * 16 + l15;
      float bb = bias[col];
#pragma unroll
      for (int i = 0; i < 4; ++i)
#pragma unroll
        for (int r = 0; r < 4; ++r)
          lds[base + (j * 16 + l15) * 130 + (qr * 64 + i * 16 + qd * 4 + r)] =
              f2bf(acc[i][j][r] + bb);
    }
    __syncthreads();
    us* Vt = (us*)(z ? V1_ : V0_);
    int b_ = row0 >> 11, seq0 = row0 & 2047;
    for (int c = t; c < 2048; c += 256) {
      int hh = c >> 10, cc = c & 1023;
      int dloc = cc >> 4, scc = cc & 15;
      int h = (coltile - 2) * 2 + hh;
      uint4 d = *(const uint4*)&lds[hh * 8320 + dloc * 130 + scc * 8];
      *(uint4*)&Vt[((size_t)(b_ * NH + h) * HD + dloc) * SEQ + seq0 + scc * 8] = d;
    }
    return;
  }

#pragma unroll
  for (int j = 0; j < 4; ++j) {
    int col = col0 + qc * 64 + j * 16 + l15;
    float bb = bias[col];
#pragma unroll
    for (int i = 0; i < MI; ++i)
#pragma unroll
      for (int r = 0; r < 4; ++r) {
        size_t grow = row0 + qr * (MI * 16) + i * 16 + qd * 4 + r;
        float v = acc[i][j][r] + bb;
        if (MODE == 0) {
          ((us*)(z ? C1_ : C0_))[grow * 256 + col] = f2bf(v * QKSCALE);
        } else if (MODE == 1) {
          ((us*)(z ? C1_ : C0_))[grow * 512 + col] = f2bf(v);
        } else {
          const float* R = z ? r1_ : r0_;
          ((float*)(z ? C1_ : C0_))[grow * 256 + col] = R[grow * 256 + col] + v;
        }
      }
  }
}

// ---------------------------------------------------------------------------
// flash_v7: register-P MFMA flash, kv-split x2, both dirs, double-buffered
// DMA prefetch, v_perm P-packing, XCD-AWARE REMAP: all 32 blocks sharing one
// (dir,b,h) K/V stream (~2MB incl. 4 heads of one (dir,b)) land on one XCD
// -> prefetch L2-hits. Block = 128 q-rows, wave = 32.
// ---------------------------------------------------------------------------
__global__ __launch_bounds__(256) void flash_v7(
    const us* __restrict__ qk0, const us* __restrict__ qk1,
    const us* __restrict__ vt0, const us* __restrict__ vt1,
    float* __restrict__ Opart, float* __restrict__ lpart) {
  __shared__ us lds[16384];  // 2 x 16KB buffers
  const int t = threadIdx.x, w = t >> 6, lane = t & 63;
  const int qd = lane >> 4, l15 = lane & 15;

  // XCD remap: xcd picks (dir,b); slot picks head + q-tile + kv-half.
  const int flat = blockIdx.x + 32 * (blockIdx.y + 4 * blockIdx.z);
  const int xcd = flat & 7, slot = flat >> 3;      // slot in [0,128)
  const int combo = (xcd << 2) + (slot >> 5);      // [0,32)
  const int qs = slot & 31;
  const int qt = qs & 15, half = qs >> 4;
  const int dir = combo >> 4, bh = combo & 15, b = bh >> 2, h = bh & 3;

  const us* Qb = dir ? qk1 : qk0;
  const us* Kb = dir ? qk0 : qk1;
  const us* Vt = dir ? vt0 : vt1;
  float* Op = Opart + (size_t)(dir * 2 + half) * (MROWS * DMODEL);
  float* lp = lpart + ((size_t)(dir * 2 + half) * NH + h) * MROWS;
  const size_t qrow0 = (size_t)b * SEQ + (size_t)qt * 128;
  const int hoff = h * HD;
  const us* vtb = Vt + (size_t)(b * NH + h) * HD * SEQ;
  const int kt0 = half * 16;

  // Hoisted per-wave DMA source pointers (4 granule tasks per wave).
  const us* sp[4];
  int sstr[4];
#pragma unroll
  for (int pp = 0; pp < 4; ++pp) {
    int g = pp * 4 + w;
    if (g < 8) {
      int tk = g >> 1, s = g & 1;
      int kvl = (tk >> 1) * 32 + (l15 >> 2) * 8 + (tk & 1) * 4 + (l15 & 3);  // pi
      sp[pp] = &Kb[(size_t)(b * SEQ + kt0 * 64 + kvl) * DMODEL + hoff + s * 32 + qd * 8];
      sstr[pp] = 64 * DMODEL;
    } else {
      int td = (g - 8) >> 1, s = g & 1;
      sp[pp] = &vtb[(size_t)(td * 16 + l15) * SEQ + kt0 * 64 + s * 32 + qd * 8];
      sstr[pp] = 64;
    }
  }

  bf16x8 qf[2][2];
#pragma unroll
  for (int qh = 0; qh < 2; ++qh)
#pragma unroll
    for (int s = 0; s < 2; ++s)
      qf[qh][s] = *(const bf16x8*)&Qb[(qrow0 + w * 32 + qh * 16 + l15) * DMODEL + hoff + s * 32 + qd * 8];

  f32x4 Oacc[2][4];
#pragma unroll
  for (int qh = 0; qh < 2; ++qh)
#pragma unroll
    for (int td = 0; td < 4; ++td) Oacc[qh][td] = (f32x4){0.f, 0.f, 0.f, 0.f};
  float l_lane[2] = {0.f, 0.f};

  // Prologue: stage tile kt0 into buffer 0.
#pragma unroll
  for (int pp = 0; pp < 4; ++pp) {
    dma16(sp[pp], &lds[(pp * 4 + w) * 512]);
    sp[pp] += sstr[pp];
  }
  __syncthreads();

  int bsel = 0;
  for (int it = 0; it < 16; ++it) {
    if (it < 15) {
#pragma unroll
      for (int pp = 0; pp < 4; ++pp) {
        dma16(sp[pp], &lds[(bsel ^ 1) * 8192 + (pp * 4 + w) * 512]);
        sp[pp] += sstr[pp];
      }
    }
    const us* L = &lds[bsel * 8192];

    bf16x8 kf[4][2], vf[4][2];
#pragma unroll
    for (int tk = 0; tk < 4; ++tk)
#pragma unroll
      for (int s = 0; s < 2; ++s) {
        kf[tk][s] = *(const bf16x8*)&L[((tk * 2 + s) * 64 + lane) * 8];
        vf[tk][s] = *(const bf16x8*)&L[((8 + tk * 2 + s) * 64 + lane) * 8];
      }

#pragma unroll
    for (int qh = 0; qh < 2; ++qh) {
      f32x4 S[4];
#pragma unroll
      for (int tk = 0; tk < 4; ++tk) {
        f32x4 a = {0.f, 0.f, 0.f, 0.f};
        a = __builtin_amdgcn_mfma_f32_16x16x32_bf16(kf[tk][0], qf[qh][0], a, 0, 0, 0);
        a = __builtin_amdgcn_mfma_f32_16x16x32_bf16(kf[tk][1], qf[qh][1], a, 0, 0, 0);
        S[tk] = a;  // pre-scaled logits[kv = pi(tk, qd*4+r)][q = l15]
      }
      float p[4][4];
      float rs = 0.f;
#pragma unroll
      for (int tk = 0; tk < 4; ++tk)
#pragma unroll
        for (int r = 0; r < 4; ++r) {
          float pv = EXP2(S[tk][r]);
          p[tk][r] = pv;
          rs += pv;
        }
      l_lane[qh] += rs;
      union { bf16x8 v; unsigned int u[4]; } pk0, pk1;
      pk0.u[0] = pk2bf(p[0][0], p[0][1]);
      pk0.u[1] = pk2bf(p[0][2], p[0][3]);
      pk0.u[2] = pk2bf(p[1][0], p[1][1]);
      pk0.u[3] = pk2bf(p[1][2], p[1][3]);
      pk1.u[0] = pk2bf(p[2][0], p[2][1]);
      pk1.u[1] = pk2bf(p[2][2], p[2][3]);
      pk1.u[2] = pk2bf(p[3][0], p[3][1]);
      pk1.u[3] = pk2bf(p[3][2], p[3][3]);
#pragma unroll
      for (int td = 0; td < 4; ++td) {
        Oacc[qh][td] = __builtin_amdgcn_mfma_f32_16x16x32_bf16(pk0.v, vf[td][0], Oacc[qh][td], 0, 0, 0);
        Oacc[qh][td] = __builtin_amdgcn_mfma_f32_16x16x32_bf16(pk1.v, vf[td][1], Oacc[qh][td], 0, 0, 0);
      }
    }
    __syncthreads();
    bsel ^= 1;
  }

  // Partials: per-row l and fp32 O-numerator (C-layout scatter).
#pragma unroll
  for (int qh = 0; qh < 2; ++qh) {
    float l = l_lane[qh];
    l += __shfl_xor(l, 16);
    l += __shfl_xor(l, 32);
    if (qd == 0) lp[qrow0 + w * 32 + qh * 16 + l15] = l;
#pragma unroll
    for (int r = 0; r < 4; ++r) {
      size_t row = qrow0 + w * 32 + qh * 16 + qd * 4 + r;
#pragma unroll
      for (int td = 0; td < 4; ++td)
        Op[row * DMODEL + hoff + td * 16 + l15] = Oacc[qh][td][r];
    }
  }
}

// ---------------------------------------------------------------------------
// Merge kv-halves: m = (Oa + Ob) / (la + lb), bf16 out.
// ---------------------------------------------------------------------------
__global__ __launch_bounds__(256) void combine_k(
    const float* __restrict__ Opart, const float* __restrict__ lpart,
    us* __restrict__ m0b, us* __restrict__ m1b) {
  int gid = blockIdx.x * 256 + threadIdx.x;
  int dir = gid >= (MROWS * DMODEL / 4);
  int idx = gid - dir * (MROWS * DMODEL / 4);
  int row = idx >> 6;
  int c4 = (idx & 63) << 2;
  int h = c4 >> 6;
  const float* Oa = Opart + (size_t)(dir * 2 + 0) * (MROWS * DMODEL);
  const float* Ob = Opart + (size_t)(dir * 2 + 1) * (MROWS * DMODEL);
  float la = lpart[((size_t)(dir * 2 + 0) * NH + h) * MROWS + row];
  float lb = lpart[((size_t)(dir * 2 + 1) * NH + h) * MROWS + row];
  float inv = 1.0f / (la + lb);
  float4 a = *(const float4*)&Oa[(size_t)row * DMODEL + c4];
  float4 bv = *(const float4*)&Ob[(size_t)row * DMODEL + c4];
  us* m = dir ? m1b : m0b;
  ushort4 o = {f2bf((a.x + bv.x) * inv), f2bf((a.y + bv.y) * inv),
               f2bf((a.z + bv.z) * inv), f2bf((a.w + bv.w) * inv)};
  *(ushort4*)&m[(size_t)row * DMODEL + c4] = o;
}

// ---------------------------------------------------------------------------
// LayerNorm(512) + exact GELU: one wave per row.
// ---------------------------------------------------------------------------
__global__ __launch_bounds__(256) void ln_gelu3(
    us* __restrict__ Y0, us* __restrict__ Y1,
    const float* __restrict__ sc, const float* __restrict__ bi) {
  int w = threadIdx.x >> 6, lane = threadIdx.x & 63;
  int ridx = blockIdx.x * 4 + w;
  us* Y = (ridx >= MROWS) ? Y1 : Y0;
  int row = ridx & (MROWS - 1);
  us* p = Y + (size_t)row * 512 + lane * 8;
  uint4 u = *(const uint4*)p;
  unsigned int uu[4] = {u.x, u.y, u.z, u.w};
  float v[8];
#pragma unroll
  for (int i = 0; i < 4; ++i) {
    v[2 * i] = bf2f((us)(uu[i] & 0xFFFF));
    v[2 * i + 1] = bf2f((us)(uu[i] >> 16));
  }
  float s1 = 0.f, s2 = 0.f;
#pragma unroll
  for (int i = 0; i < 8; ++i) { s1 += v[i]; s2 += v[i] * v[i]; }
#pragma unroll
  for (int m = 1; m < 64; m <<= 1) {
    s1 += __shfl_xor(s1, m);
    s2 += __shfl_xor(s2, m);
  }
  float mu = s1 * (1.0f / 512.0f);
  float var = s2 * (1.0f / 512.0f) - mu * mu;
  float rstd = rsqrtf(var + 1e-5f);
  int c0 = lane * 8;
  float4 scA = *(const float4*)&sc[c0], scB = *(const float4*)&sc[c0 + 4];
  float4 biA = *(const float4*)&bi[c0], biB = *(const float4*)&bi[c0 + 4];
  float scv[8] = {scA.x, scA.y, scA.z, scA.w, scB.x, scB.y, scB.z, scB.w};
  float biv[8] = {biA.x, biA.y, biA.z, biA.w, biB.x, biB.y, biB.z, biB.w};
  unsigned int ou[4];
#pragma unroll
  for (int i = 0; i < 4; ++i) {
    float y0 = (v[2 * i] - mu) * rstd * scv[2 * i] + biv[2 * i];
    float y1 = (v[2 * i + 1] - mu) * rstd * scv[2 * i + 1] + biv[2 * i + 1];
    y0 = 0.5f * y0 * (1.0f + erff(y0 * 0.70710678118654752f));
    y1 = 0.5f * y1 * (1.0f + erff(y1 * 0.70710678118654752f));
    ou[i] = (unsigned int)f2bf(y0) | ((unsigned int)f2bf(y1) << 16);
  }
  uint4 o = {ou[0], ou[1], ou[2], ou[3]};
  *(uint4*)p = o;
}

// ---------------------------------------------------------------------------
// Workspace (byte offsets), total 67 MB, stream-order-safe aliasing:
//   0/4 MB: x0b,x1b | 8 MB: Wqvt, W1t, W3t | 9 MB: biases
//   10/14: qk0b,qk1b | 18/22: vt0,vt1 | 26/30: m0b,m1b
//   y0b/y1b overlay 10-26 | 34-66: Opart[4] fp32 | 66: lpart
// ---------------------------------------------------------------------------
extern "C" void kernel_launch(void* const* d_in, const int* in_sizes, int n_in,
                              void* d_out, int out_size, void* d_ws,
                              size_t ws_size, hipStream_t stream) {
  const float* x0   = (const float*)d_in[0];
  const float* x1   = (const float*)d_in[1];
  const float* Wqk  = (const float*)d_in[2];
  const float* bqk  = (const float*)d_in[3];
  const float* Wv   = (const float*)d_in[4];
  const float* bv   = (const float*)d_in[5];
  const float* Wout = (const float*)d_in[6];
  const float* bout = (const float*)d_in[7];
  const float* W0   = (const float*)d_in[8];
  const float* b0   = (const float*)d_in[9];
  const float* lns  = (const float*)d_in[10];
  const float* lnb  = (const float*)d_in[11];
  const float* W3   = (const float*)d_in[12];
  const float* b3   = (const float*)d_in[13];

  char* ws = (char*)d_ws;
  const size_t MB = 1024 * 1024;
  us* x0b  = (us*)(ws + 0 * MB);
  us* x1b  = (us*)(ws + 4 * MB);
  us* Wqvt = (us*)(ws + 8 * MB);
  us* W1t  = (us*)(ws + 8 * MB + 262144);
  us* W3t  = (us*)(ws + 8 * MB + 786432);
  float* bias_qv = (float*)(ws + 9 * MB);
  float* bias1   = (float*)(ws + 9 * MB + 4096);
  us* qk0b = (us*)(ws + 10 * MB);
  us* qk1b = (us*)(ws + 14 * MB);
  us* vt0  = (us*)(ws + 18 * MB);
  us* vt1  = (us*)(ws + 22 * MB);
  us* m0b  = (us*)(ws + 26 * MB);
  us* m1b  = (us*)(ws + 30 * MB);
  us* y0b  = (us*)(ws + 10 * MB);  // overlay qk (dead after flash)
  us* y1b  = (us*)(ws + 18 * MB);  // overlay vt (dead after combine)
  float* Opart = (float*)(ws + 34 * MB);
  float* lpart = (float*)(ws + 66 * MB);
  float* out0 = (float*)d_out;
  float* out1 = out0 + (size_t)MROWS * DMODEL;

  dim3 blk(256);

  prep_k<<<dim3(5891), blk, 0, stream>>>(x0, x1, Wqk, Wv, W0, W3, Wout,
                                         bqk, bv, b0, bout,
                                         x0b, x1b, Wqvt, W1t, W3t,
                                         bias_qv, bias1);

  // QK+V projection fused (N=512): coltile 0-1 qk scaled, 2-3 vt transposed
  gemm5<0><<<dim3(64, 4, 2), blk, 0, stream>>>(
      x0b, x1b, nullptr, nullptr, Wqvt, bias_qv, nullptr, nullptr,
      qk0b, qk1b, vt0, vt1, 256);

  // Bidirectional cross attention, kv-split x2, both dirs fused
  flash_v7<<<dim3(32, 4, 8), blk, 0, stream>>>(qk0b, qk1b, vt0, vt1, Opart, lpart);
  combine_k<<<dim3(4096), blk, 0, stream>>>(Opart, lpart, m0b, m1b);

  // FFN1 (out-proj folded): y = concat(x, m) @ [W0top; Wcomb] + bias1
  gemm5<1><<<dim3(64, 4, 2), blk, 0, stream>>>(
      x0b, x1b, m0b, m1b, W1t, bias1, nullptr, nullptr,
      y0b, y1b, nullptr, nullptr, 512);

  ln_gelu3<<<dim3(4096), blk, 0, stream>>>(y0b, y1b, lns, lnb);

  // FFN2: out = x + y @ W3 + b3 (fp32)
  gemm5<2><<<dim3(64, 4, 2), blk, 0, stream>>>(
      y0b, y1b, nullptr, nullptr, W3t, b3, x0, x1,
      out0, out1, nullptr, nullptr, 512);
}